// Round 1
// baseline (307.757 us; speedup 1.0000x reference)
//
#include <hip/hip_runtime.h>
#include <hip/hip_bf16.h>
#include <math.h>

#define HID 1024
#define INTER 8192
#define TT 4096  // tokens = B*S

typedef __bf16 bf16x8 __attribute__((ext_vector_type(8)));
typedef float f32x4 __attribute__((ext_vector_type(4)));

__device__ __forceinline__ void gll16(const void* g, void* l) {
    __builtin_amdgcn_global_load_lds(
        (const __attribute__((address_space(1))) void*)g,
        (__attribute__((address_space(3))) void*)l, 16, 0, 0);
}

// cast x -> bf16, compute per-token scale s[t] = ew[t,0]+ew[t,1]
__global__ void k_prep(const float* __restrict__ x, const float* __restrict__ ew,
                       __hip_bfloat16* __restrict__ xb, float* __restrict__ s,
                       int n4, int T) {
    int stride = gridDim.x * blockDim.x;
    for (int i = blockIdx.x * blockDim.x + threadIdx.x; i < n4; i += stride) {
        float4 v = ((const float4*)x)[i];
        __hip_bfloat16* o = xb + (size_t)i * 4;
        o[0] = __float2bfloat16(v.x);
        o[1] = __float2bfloat16(v.y);
        o[2] = __float2bfloat16(v.z);
        o[3] = __float2bfloat16(v.w);
    }
    for (int t = blockIdx.x * blockDim.x + threadIdx.x; t < T; t += stride)
        s[t] = ew[2 * t] + ew[2 * t + 1];
}

// transpose + cast: in f32 [R][C] -> out bf16 [C][R]
__global__ void k_tcast(const float* __restrict__ in, __hip_bfloat16* __restrict__ out,
                        int R, int C) {
    __shared__ float tile[32][33];
    const int tx = threadIdx.x & 31, ty = threadIdx.x >> 5;  // 32x8
    const int br = blockIdx.y * 32, bc = blockIdx.x * 32;
#pragma unroll
    for (int j = 0; j < 32; j += 8)
        tile[ty + j][tx] = in[(size_t)(br + ty + j) * C + bc + tx];
    __syncthreads();
#pragma unroll
    for (int j = 0; j < 32; j += 8)
        out[(size_t)(bc + ty + j) * R + br + tx] = __float2bfloat16(tile[tx][ty + j]);
}

// C = A[M,K] * Bt[N,K]^T ; EPI=0: gelu->bf16 hOut ; EPI=1: s[row]*acc -> f32 fOut
template <int EPI>
__global__ __launch_bounds__(256) void k_gemm(
    const __hip_bfloat16* __restrict__ A, const __hip_bfloat16* __restrict__ Bt,
    __hip_bfloat16* __restrict__ hOut, float* __restrict__ fOut,
    const float* __restrict__ s, int M, int N, int K) {
    __shared__ __hip_bfloat16 As[128 * 32];
    __shared__ __hip_bfloat16 Bs[128 * 32];
    const int tid = threadIdx.x;
    const int wave = tid >> 6;
    const int lane = tid & 63;
    const int wr = wave >> 1, wc = wave & 1;
    const int bRow = blockIdx.y * 128, bCol = blockIdx.x * 128;
    const int lrow = lane & 15, lk8 = (lane >> 4) * 8;

    f32x4 acc[4][4] = {};

    const __hip_bfloat16* gA = A + (size_t)(bRow + (tid >> 2)) * K + (tid & 3) * 8;
    const __hip_bfloat16* gB = Bt + (size_t)(bCol + (tid >> 2)) * K + (tid & 3) * 8;
    char* ldsA = (char*)&As[0] + wave * 1024;
    char* ldsB = (char*)&Bs[0] + wave * 1024;
    const size_t rstride = (size_t)64 * K;

    for (int k0 = 0; k0 < K; k0 += 32) {
        __syncthreads();
        gll16(gA, ldsA);
        gll16(gA + rstride, ldsA + 4096);
        gll16(gB, ldsB);
        gll16(gB + rstride, ldsB + 4096);
        gA += 32;
        gB += 32;
        __syncthreads();
        bf16x8 af[4], bfr[4];
#pragma unroll
        for (int m = 0; m < 4; ++m)
            af[m] = *(const bf16x8*)&As[(wr * 64 + m * 16 + lrow) * 32 + lk8];
#pragma unroll
        for (int n = 0; n < 4; ++n)
            bfr[n] = *(const bf16x8*)&Bs[(wc * 64 + n * 16 + lrow) * 32 + lk8];
#pragma unroll
        for (int m = 0; m < 4; ++m)
#pragma unroll
            for (int n = 0; n < 4; ++n)
                acc[m][n] = __builtin_amdgcn_mfma_f32_16x16x32_bf16(af[m], bfr[n],
                                                                    acc[m][n], 0, 0, 0);
    }

    const int orow = bRow + wr * 64 + (lane >> 4) * 4;
    const int ocol = bCol + wc * 64 + lrow;
#pragma unroll
    for (int m = 0; m < 4; ++m) {
#pragma unroll
        for (int j = 0; j < 4; ++j) {
            const int r = orow + m * 16 + j;
            const size_t ro = (size_t)r * N;
            if (EPI == 0) {
#pragma unroll
                for (int n = 0; n < 4; ++n) {
                    float v = acc[m][n][j];
                    float g = 0.5f * v *
                              (1.0f + tanhf(0.7978845608028654f * (v + 0.044715f * v * v * v)));
                    hOut[ro + ocol + n * 16] = __float2bfloat16(g);
                }
            } else {
                const float sc = s[r];
#pragma unroll
                for (int n = 0; n < 4; ++n)
                    fOut[ro + ocol + n * 16] = sc * acc[m][n][j];
            }
        }
    }
}

extern "C" void kernel_launch(void* const* d_in, const int* in_sizes, int n_in,
                              void* d_out, int out_size, void* d_ws, size_t ws_size,
                              hipStream_t stream) {
    const float* x = (const float*)d_in[0];
    // d_in[1] = scores (unused), d_in[3] = top_experts (unused)
    const float* ew = (const float*)d_in[2];
    const float* w1 = (const float*)d_in[4];
    const float* w2 = (const float*)d_in[5];
    float* out = (float*)d_out;

    char* ws = (char*)d_ws;
    float* s = (float*)ws;                                               // 16 KB
    __hip_bfloat16* xb = (__hip_bfloat16*)(ws + 16384);                  // 8 MB
    __hip_bfloat16* w1t = (__hip_bfloat16*)(ws + 16384 + 8388608);       // 16 MB
    __hip_bfloat16* w2t = (__hip_bfloat16*)(ws + 16384 + 8388608 + 16777216);  // 16 MB
    __hip_bfloat16* h = (__hip_bfloat16*)(ws + 16384 + 8388608 + 2 * 16777216);  // 64 MB

    k_prep<<<1024, 256, 0, stream>>>(x, ew, xb, s, (TT * HID) / 4, TT);

    dim3 t1(INTER / 32, HID / 32);  // w1: R=1024, C=8192
    k_tcast<<<t1, 256, 0, stream>>>(w1, w1t, HID, INTER);
    dim3 t2(HID / 32, INTER / 32);  // w2: R=8192, C=1024
    k_tcast<<<t2, 256, 0, stream>>>(w2, w2t, INTER, HID);

    dim3 g1(INTER / 128, TT / 128);  // 64 x 32
    k_gemm<0><<<g1, 256, 0, stream>>>(xb, w1t, h, nullptr, nullptr, TT, INTER, HID);
    dim3 g2(HID / 128, TT / 128);  // 8 x 32
    k_gemm<1><<<g2, 256, 0, stream>>>(h, w2t, nullptr, out, s, TT, HID, INTER);
}

// Round 2
// 218.394 us; speedup vs baseline: 1.4092x; 1.4092x over previous
//
#include <hip/hip_runtime.h>
#include <hip/hip_bf16.h>
#include <math.h>

#define HID 1024
#define INTER 8192
#define TT 4096  // tokens = B*S

typedef __bf16 bf16x8 __attribute__((ext_vector_type(8)));
typedef float f32x4 __attribute__((ext_vector_type(4)));

__device__ __forceinline__ void gll16(const void* g, void* l) {
    __builtin_amdgcn_global_load_lds(
        (const __attribute__((address_space(1))) void*)g,
        (__attribute__((address_space(3))) void*)l, 16, 0, 0);
}

// cast x -> bf16, compute per-token scale s[t] = ew[t,0]+ew[t,1]
__global__ void k_prep(const float* __restrict__ x, const float* __restrict__ ew,
                       __hip_bfloat16* __restrict__ xb, float* __restrict__ s,
                       int n4, int T) {
    int stride = gridDim.x * blockDim.x;
    for (int i = blockIdx.x * blockDim.x + threadIdx.x; i < n4; i += stride) {
        float4 v = ((const float4*)x)[i];
        __hip_bfloat16* o = xb + (size_t)i * 4;
        o[0] = __float2bfloat16(v.x);
        o[1] = __float2bfloat16(v.y);
        o[2] = __float2bfloat16(v.z);
        o[3] = __float2bfloat16(v.w);
    }
    for (int t = blockIdx.x * blockDim.x + threadIdx.x; t < T; t += stride)
        s[t] = ew[2 * t] + ew[2 * t + 1];
}

// transpose + cast: in f32 [R][C] -> out bf16 [C][R]
__global__ void k_tcast(const float* __restrict__ in, __hip_bfloat16* __restrict__ out,
                        int R, int C) {
    __shared__ float tile[32][33];
    const int tx = threadIdx.x & 31, ty = threadIdx.x >> 5;  // 32x8
    const int br = blockIdx.y * 32, bc = blockIdx.x * 32;
#pragma unroll
    for (int j = 0; j < 32; j += 8)
        tile[ty + j][tx] = in[(size_t)(br + ty + j) * C + bc + tx];
    __syncthreads();
#pragma unroll
    for (int j = 0; j < 32; j += 8)
        out[(size_t)(bc + ty + j) * R + br + tx] = __float2bfloat16(tile[tx][ty + j]);
}

// ---------------------------------------------------------------------------
// 256x256 tile, BK=64, 8 waves (2Mx4N), 8-phase schedule, counted vmcnt,
// st-style XOR swizzle (granule ^= row&7) applied on global source + LDS read.
// EPI=0: gelu -> bf16 hOut.   EPI=1: unsafeAtomicAdd(s[row]*acc) into f32 fOut.
// A [M rows][Kfull], Bt [N rows][Kfull]; block covers K sub-range
// [blockIdx.z*nt*64, +nt*64).
// ---------------------------------------------------------------------------
template <int EPI>
__global__ __launch_bounds__(512, 2) void k_gemm8(
    const __hip_bfloat16* __restrict__ A, const __hip_bfloat16* __restrict__ Bt,
    __hip_bfloat16* __restrict__ hOut, float* __restrict__ fOut,
    const float* __restrict__ s, int Kfull, int nt, int Nout) {
    __shared__ __hip_bfloat16 sA[2][2][128][64];  // [buf][half][row][k]
    __shared__ __hip_bfloat16 sB[2][2][128][64];
    const int tid = threadIdx.x;
    const int lane = tid & 63, wid = tid >> 6;
    const int wr = wid >> 2, wc = wid & 3;  // 2x4 wave grid; wave tile 128x64

    // XCD-bijective swizzle over flattened (y,x); nwg % 8 == 0 by construction.
    const int nwg = gridDim.x * gridDim.y;
    const int wg = blockIdx.y * gridDim.x + blockIdx.x;
    const int swz = (wg & 7) * (nwg >> 3) + (wg >> 3);
    const int brow = (swz / gridDim.x) * 256;
    const int bcol = (swz % gridDim.x) * 256;
    const size_t kbase = (size_t)blockIdx.z * ((size_t)nt * 64);

    // staging: thread t loads 16B granule (t&7), row (t>>3) (+64 on round 1);
    // global col pre-swizzled so linear LDS dest + swizzled read match (#21).
    const int rstage = tid >> 3;
    const int colsw = (((tid & 7) ^ (rstage & 7)) << 3);  // elements
    const __hip_bfloat16* gA = A + (size_t)(brow + rstage) * Kfull + kbase + colsw;
    const __hip_bfloat16* gB = Bt + (size_t)(bcol + rstage) * Kfull + kbase + colsw;
    const size_t rowStep = (size_t)64 * Kfull;
    const size_t halfStep = (size_t)128 * Kfull;

    char* ldsA0 = (char*)&sA[0][0][0][0] + wid * 1024;
    char* ldsB0 = (char*)&sB[0][0][0][0] + wid * 1024;

    // read-side swizzled granule byte offsets for ks=0,1
    const int g0 = (((lane >> 4)) ^ (lane & 7)) << 4;
    const int g1 = ((4 + (lane >> 4)) ^ (lane & 7)) << 4;
    const char* rdA = (const char*)&sA[0][wr][0][0] + (lane & 15) * 128;
    const char* rdB = (const char*)&sB[0][wc >> 1][0][0] + (wc & 1) * 8192 + (lane & 15) * 128;

    f32x4 acc[8][4] = {};
    bf16x8 aF[4][2], b01[2][2], b23[2][2];

#define STAGE_A(buf, half, t)                                              \
    do {                                                                   \
        const __hip_bfloat16* _g = gA + (half) * halfStep + (size_t)(t) * 64; \
        char* _l = ldsA0 + (buf) * 32768 + (half) * 16384;                 \
        gll16(_g, _l);                                                     \
        gll16(_g + rowStep, _l + 8192);                                    \
    } while (0)
#define STAGE_B(buf, half, t)                                              \
    do {                                                                   \
        const __hip_bfloat16* _g = gB + (half) * halfStep + (size_t)(t) * 64; \
        char* _l = ldsB0 + (buf) * 32768 + (half) * 16384;                 \
        gll16(_g, _l);                                                     \
        gll16(_g + rowStep, _l + 8192);                                    \
    } while (0)
#define BAR()                              \
    do {                                   \
        asm volatile("" ::: "memory");     \
        __builtin_amdgcn_s_barrier();      \
        asm volatile("" ::: "memory");     \
    } while (0)
#define WAITLG() asm volatile("s_waitcnt lgkmcnt(0)" ::: "memory")
#define RD(base, buf, r2048, ks) \
    (*(const bf16x8*)((base) + (buf) * 32768 + (r2048) * 2048 + ((ks) ? g1 : g0)))
#define MM_Q(mbase, nbase, bfr)                                                   \
    _Pragma("unroll") for (int ks = 0; ks < 2; ++ks)                              \
    _Pragma("unroll") for (int m = 0; m < 4; ++m)                                 \
    _Pragma("unroll") for (int n = 0; n < 2; ++n)                                 \
        acc[(mbase) + m][(nbase) + n] = __builtin_amdgcn_mfma_f32_16x16x32_bf16(  \
            aF[m][ks], bfr[n][ks], acc[(mbase) + m][(nbase) + n], 0, 0, 0);

    // prologue: tile0 (all 4 halves, buf0) + tile1 B-halves (buf1); keep last
    // 4 loads (tile1.Bh) in flight.
    STAGE_B(0, 0, 0);
    STAGE_B(0, 1, 0);
    STAGE_A(0, 0, 0);
    STAGE_A(0, 1, 0);
    STAGE_B(1, 0, 1);
    STAGE_B(1, 1, 1);
    asm volatile("s_waitcnt vmcnt(4)" ::: "memory");
    BAR();

    const int iters = nt >> 1;
    for (int i = 0; i < iters; ++i) {
        const bool full = (i + 1 < iters);
        const int t1 = 2 * i + 1, t2 = 2 * i + 2, t3 = 2 * i + 3;

        // phase 1: tile 2i (buf0): A[m0-3], B[n0-1]; MFMA m0-3 x n0-1
#pragma unroll
        for (int m = 0; m < 4; ++m) {
            aF[m][0] = RD(rdA, 0, m, 0);
            aF[m][1] = RD(rdA, 0, m, 1);
        }
#pragma unroll
        for (int n = 0; n < 2; ++n) {
            b01[n][0] = RD(rdB, 0, n, 0);
            b01[n][1] = RD(rdB, 0, n, 1);
        }
        STAGE_A(1, 0, t1);
        BAR();
        WAITLG();
        __builtin_amdgcn_s_setprio(1);
        MM_Q(0, 0, b01);
        __builtin_amdgcn_s_setprio(0);
        BAR();

        // phase 2: B[n2-3]; MFMA m0-3 x n2-3
#pragma unroll
        for (int n = 0; n < 2; ++n) {
            b23[n][0] = RD(rdB, 0, 2 + n, 0);
            b23[n][1] = RD(rdB, 0, 2 + n, 1);
        }
        STAGE_A(1, 1, t1);
        BAR();
        WAITLG();
        __builtin_amdgcn_s_setprio(1);
        MM_Q(0, 2, b23);
        __builtin_amdgcn_s_setprio(0);
        BAR();

        // phase 3: A[m4-7]; MFMA m4-7 x n2-3
#pragma unroll
        for (int m = 0; m < 4; ++m) {
            aF[m][0] = RD(rdA, 0, 4 + m, 0);
            aF[m][1] = RD(rdA, 0, 4 + m, 1);
        }
        if (full) STAGE_B(0, 0, t2);
        BAR();
        WAITLG();
        __builtin_amdgcn_s_setprio(1);
        MM_Q(4, 2, b23);
        __builtin_amdgcn_s_setprio(0);
        BAR();

        // phase 4: no ds_read; MFMA m4-7 x n0-1 (b01 kept in regs)
        if (full) STAGE_B(0, 1, t2);
        BAR();
        __builtin_amdgcn_s_setprio(1);
        MM_Q(4, 0, b01);
        __builtin_amdgcn_s_setprio(0);
        if (full)
            asm volatile("s_waitcnt vmcnt(4)" ::: "memory");
        else
            asm volatile("s_waitcnt vmcnt(0)" ::: "memory");
        BAR();

        // phase 5: tile 2i+1 (buf1): A[m0-3], B[n0-1]
#pragma unroll
        for (int m = 0; m < 4; ++m) {
            aF[m][0] = RD(rdA, 1, m, 0);
            aF[m][1] = RD(rdA, 1, m, 1);
        }
#pragma unroll
        for (int n = 0; n < 2; ++n) {
            b01[n][0] = RD(rdB, 1, n, 0);
            b01[n][1] = RD(rdB, 1, n, 1);
        }
        if (full) STAGE_A(0, 0, t2);
        BAR();
        WAITLG();
        __builtin_amdgcn_s_setprio(1);
        MM_Q(0, 0, b01);
        __builtin_amdgcn_s_setprio(0);
        BAR();

        // phase 6: B[n2-3]
#pragma unroll
        for (int n = 0; n < 2; ++n) {
            b23[n][0] = RD(rdB, 1, 2 + n, 0);
            b23[n][1] = RD(rdB, 1, 2 + n, 1);
        }
        if (full) STAGE_A(0, 1, t2);
        BAR();
        WAITLG();
        __builtin_amdgcn_s_setprio(1);
        MM_Q(0, 2, b23);
        __builtin_amdgcn_s_setprio(0);
        BAR();

        // phase 7: A[m4-7]
#pragma unroll
        for (int m = 0; m < 4; ++m) {
            aF[m][0] = RD(rdA, 1, 4 + m, 0);
            aF[m][1] = RD(rdA, 1, 4 + m, 1);
        }
        if (full) STAGE_B(1, 0, t3);
        BAR();
        WAITLG();
        __builtin_amdgcn_s_setprio(1);
        MM_Q(4, 2, b23);
        __builtin_amdgcn_s_setprio(0);
        BAR();

        // phase 8: MFMA m4-7 x n0-1
        if (full) STAGE_B(1, 1, t3);
        BAR();
        __builtin_amdgcn_s_setprio(1);
        MM_Q(4, 0, b01);
        __builtin_amdgcn_s_setprio(0);
        if (full)
            asm volatile("s_waitcnt vmcnt(4)" ::: "memory");
        else
            asm volatile("s_waitcnt vmcnt(0)" ::: "memory");
        BAR();
    }

    // epilogue
    const int orow = brow + wr * 128 + ((lane >> 4) << 2);
    const int ocol = bcol + wc * 64 + (lane & 15);
#pragma unroll
    for (int m = 0; m < 8; ++m) {
#pragma unroll
        for (int j = 0; j < 4; ++j) {
            const int r = orow + m * 16 + j;
            const size_t ro = (size_t)r * Nout;
            if (EPI == 0) {
#pragma unroll
                for (int n = 0; n < 4; ++n) {
                    float v = acc[m][n][j];
                    float u = 1.5957691216057308f * (v + 0.044715f * v * v * v);
                    float g = v / (1.0f + __expf(-u));
                    hOut[ro + ocol + n * 16] = __float2bfloat16(g);
                }
            } else {
                const float sc = s[r];
#pragma unroll
                for (int n = 0; n < 4; ++n)
                    unsafeAtomicAdd(&fOut[ro + ocol + n * 16], sc * acc[m][n][j]);
            }
        }
    }
#undef STAGE_A
#undef STAGE_B
#undef BAR
#undef WAITLG
#undef RD
#undef MM_Q
}

extern "C" void kernel_launch(void* const* d_in, const int* in_sizes, int n_in,
                              void* d_out, int out_size, void* d_ws, size_t ws_size,
                              hipStream_t stream) {
    const float* x = (const float*)d_in[0];
    // d_in[1] = scores (unused), d_in[3] = top_experts (unused)
    const float* ew = (const float*)d_in[2];
    const float* w1 = (const float*)d_in[4];
    const float* w2 = (const float*)d_in[5];
    float* out = (float*)d_out;

    char* ws = (char*)d_ws;
    float* s = (float*)ws;                                                    // 16 KB
    __hip_bfloat16* xb = (__hip_bfloat16*)(ws + 16384);                       // 8 MB
    __hip_bfloat16* w1t = (__hip_bfloat16*)(ws + 16384 + 8388608);            // 16 MB
    __hip_bfloat16* w2t = (__hip_bfloat16*)(ws + 16384 + 8388608 + 16777216); // 16 MB
    __hip_bfloat16* h = (__hip_bfloat16*)(ws + 16384 + 8388608 + 2 * 16777216); // 64 MB

    k_prep<<<1024, 256, 0, stream>>>(x, ew, xb, s, (TT * HID) / 4, TT);

    dim3 t1(INTER / 32, HID / 32);
    k_tcast<<<t1, 256, 0, stream>>>(w1, w1t, HID, INTER);
    dim3 t2(HID / 32, INTER / 32);
    k_tcast<<<t2, 256, 0, stream>>>(w2, w2t, INTER, HID);

    // GEMM1: [4096 x 1024] x [1024 x 8192] -> h (gelu, bf16)
    dim3 g1(INTER / 256, TT / 256, 1);  // 32 x 16
    k_gemm8<0><<<g1, 512, 0, stream>>>(xb, w1t, h, nullptr, nullptr, HID, HID / 64, INTER);

    // GEMM2: [4096 x 8192] x [8192 x 1024] -> out (f32, split-K=4 atomic combine)
    hipMemsetAsync(out, 0, (size_t)TT * HID * sizeof(float), stream);
    dim3 g2(HID / 256, TT / 256, 4);  // 4 x 16 x 4 = 256 blocks
    k_gemm8<1><<<g2, 512, 0, stream>>>(h, w2t, nullptr, out, s, INTER, 2048 / 64, HID);
}

// Round 3
// 217.476 us; speedup vs baseline: 1.4151x; 1.0042x over previous
//
#include <hip/hip_runtime.h>
#include <hip/hip_bf16.h>
#include <math.h>

#define HID 1024
#define INTER 8192
#define TT 4096  // tokens = B*S

typedef __bf16 bf16x8 __attribute__((ext_vector_type(8)));
typedef float f32x4 __attribute__((ext_vector_type(4)));

__device__ __forceinline__ void gll16(const void* g, void* l) {
    __builtin_amdgcn_global_load_lds(
        (const __attribute__((address_space(1))) void*)g,
        (__attribute__((address_space(3))) void*)l, 16, 0, 0);
}

// cast x -> bf16, compute per-token scale s[t] = ew[t,0]+ew[t,1]
__global__ void k_prep(const float* __restrict__ x, const float* __restrict__ ew,
                       __hip_bfloat16* __restrict__ xb, float* __restrict__ s,
                       int n4, int T) {
    int stride = gridDim.x * blockDim.x;
    for (int i = blockIdx.x * blockDim.x + threadIdx.x; i < n4; i += stride) {
        float4 v = ((const float4*)x)[i];
        __hip_bfloat16* o = xb + (size_t)i * 4;
        o[0] = __float2bfloat16(v.x);
        o[1] = __float2bfloat16(v.y);
        o[2] = __float2bfloat16(v.z);
        o[3] = __float2bfloat16(v.w);
    }
    for (int t = blockIdx.x * blockDim.x + threadIdx.x; t < T; t += stride)
        s[t] = ew[2 * t] + ew[2 * t + 1];
}

// transpose + cast: in f32 [R][C] -> out bf16 [C][R]
__global__ void k_tcast(const float* __restrict__ in, __hip_bfloat16* __restrict__ out,
                        int R, int C) {
    __shared__ float tile[32][33];
    const int tx = threadIdx.x & 31, ty = threadIdx.x >> 5;  // 32x8
    const int br = blockIdx.y * 32, bc = blockIdx.x * 32;
#pragma unroll
    for (int j = 0; j < 32; j += 8)
        tile[ty + j][tx] = in[(size_t)(br + ty + j) * C + bc + tx];
    __syncthreads();
#pragma unroll
    for (int j = 0; j < 32; j += 8)
        out[(size_t)(bc + ty + j) * R + br + tx] = __float2bfloat16(tile[tx][ty + j]);
}

// ---------------------------------------------------------------------------
// 256x256 tile, BK=64, 8 waves (2Mx4N), 8-phase schedule, counted vmcnt,
// XOR swizzle (granule ^= row&7) on global source + LDS read (rule #21).
// sched_barrier(0) pins at phase boundaries (rule #18: "memory" clobber does
// NOT order register-only MFMA; without pins hipcc merges phases).
// EPI=0: gelu -> bf16 hOut.   EPI=1: unsafeAtomicAdd(s[row]*acc) into f32 fOut.
// ---------------------------------------------------------------------------
template <int EPI>
__global__ __launch_bounds__(512, 2) void k_gemm8(
    const __hip_bfloat16* __restrict__ A, const __hip_bfloat16* __restrict__ Bt,
    __hip_bfloat16* __restrict__ hOut, float* __restrict__ fOut,
    const float* __restrict__ s, int Kfull, int nt, int Nout) {
    __shared__ __hip_bfloat16 sA[2][2][128][64];  // [buf][half][row][k]
    __shared__ __hip_bfloat16 sB[2][2][128][64];
    const int tid = threadIdx.x;
    const int lane = tid & 63, wid = tid >> 6;
    const int wr = wid >> 2, wc = wid & 3;  // 2x4 wave grid; wave tile 128x64

    // XCD-bijective swizzle over flattened (y,x); nwg % 8 == 0 by construction.
    const int nwg = gridDim.x * gridDim.y;
    const int wg = blockIdx.y * gridDim.x + blockIdx.x;
    const int swz = (wg & 7) * (nwg >> 3) + (wg >> 3);
    const int brow = (swz / gridDim.x) * 256;
    const int bcol = (swz % gridDim.x) * 256;
    const size_t kbase = (size_t)blockIdx.z * ((size_t)nt * 64);

    // staging: thread t loads 16B granule (t&7), row (t>>3) (+64 on round 1);
    // global col pre-swizzled so linear LDS dest + swizzled read match (#21).
    const int rstage = tid >> 3;
    const int colsw = (((tid & 7) ^ (rstage & 7)) << 3);  // elements
    const __hip_bfloat16* gA = A + (size_t)(brow + rstage) * Kfull + kbase + colsw;
    const __hip_bfloat16* gB = Bt + (size_t)(bcol + rstage) * Kfull + kbase + colsw;
    const size_t rowStep = (size_t)64 * Kfull;
    const size_t halfStep = (size_t)128 * Kfull;

    char* ldsA0 = (char*)&sA[0][0][0][0] + wid * 1024;
    char* ldsB0 = (char*)&sB[0][0][0][0] + wid * 1024;

    // read-side swizzled granule byte offsets for ks=0,1
    const int g0 = (((lane >> 4)) ^ (lane & 7)) << 4;
    const int g1 = ((4 + (lane >> 4)) ^ (lane & 7)) << 4;
    const char* rdA = (const char*)&sA[0][wr][0][0] + (lane & 15) * 128;
    const char* rdB = (const char*)&sB[0][wc >> 1][0][0] + (wc & 1) * 8192 + (lane & 15) * 128;

    f32x4 acc[8][4] = {};
    bf16x8 aF[4][2], b01[2][2], b23[2][2];

#define STAGE_A(buf, half, t)                                              \
    do {                                                                   \
        const __hip_bfloat16* _g = gA + (half) * halfStep + (size_t)(t) * 64; \
        char* _l = ldsA0 + (buf) * 32768 + (half) * 16384;                 \
        gll16(_g, _l);                                                     \
        gll16(_g + rowStep, _l + 8192);                                    \
    } while (0)
#define STAGE_B(buf, half, t)                                              \
    do {                                                                   \
        const __hip_bfloat16* _g = gB + (half) * halfStep + (size_t)(t) * 64; \
        char* _l = ldsB0 + (buf) * 32768 + (half) * 16384;                 \
        gll16(_g, _l);                                                     \
        gll16(_g + rowStep, _l + 8192);                                    \
    } while (0)
#define BAR()                              \
    do {                                   \
        asm volatile("" ::: "memory");     \
        __builtin_amdgcn_s_barrier();      \
        asm volatile("" ::: "memory");     \
    } while (0)
#define WAITLG() asm volatile("s_waitcnt lgkmcnt(0)" ::: "memory")
#define PREDRAIN() asm volatile("s_waitcnt lgkmcnt(8)" ::: "memory")
#define PIN() __builtin_amdgcn_sched_barrier(0)
#define RD(base, buf, r2048, ks) \
    (*(const bf16x8*)((base) + (buf) * 32768 + (r2048) * 2048 + ((ks) ? g1 : g0)))
#define MM_Q(mbase, nbase, bfr)                                                   \
    _Pragma("unroll") for (int ks = 0; ks < 2; ++ks)                              \
    _Pragma("unroll") for (int m = 0; m < 4; ++m)                                 \
    _Pragma("unroll") for (int n = 0; n < 2; ++n)                                 \
        acc[(mbase) + m][(nbase) + n] = __builtin_amdgcn_mfma_f32_16x16x32_bf16(  \
            aF[m][ks], bfr[n][ks], acc[(mbase) + m][(nbase) + n], 0, 0, 0);
// MFMA region: nothing crosses in from above (PIN after drain) or escapes
// below (PIN after cluster).
#define MFMA_PHASE(mbase, nbase, bfr)     \
    do {                                  \
        WAITLG();                         \
        PIN();                            \
        __builtin_amdgcn_s_setprio(1);    \
        MM_Q(mbase, nbase, bfr);          \
        __builtin_amdgcn_s_setprio(0);    \
        PIN();                            \
    } while (0)

    // prologue: tile0 (all 4 halves, buf0) + tile1 B-halves (buf1).
    STAGE_B(0, 0, 0);
    STAGE_B(0, 1, 0);
    STAGE_A(0, 0, 0);
    STAGE_A(0, 1, 0);
    STAGE_B(1, 0, 1);
    STAGE_B(1, 1, 1);
    asm volatile("s_waitcnt vmcnt(4)" ::: "memory");
    BAR();

    const int iters = nt >> 1;
    for (int i = 0; i < iters; ++i) {
        const bool full = (i + 1 < iters);
        const int t1 = 2 * i + 1, t2 = 2 * i + 2, t3 = 2 * i + 3;

        // phase 1: tile 2i (buf0): read A[m0-3]+B[n0-1]; MFMA m0-3 x n0-1
#pragma unroll
        for (int m = 0; m < 4; ++m) {
            aF[m][0] = RD(rdA, 0, m, 0);
            aF[m][1] = RD(rdA, 0, m, 1);
        }
#pragma unroll
        for (int n = 0; n < 2; ++n) {
            b01[n][0] = RD(rdB, 0, n, 0);
            b01[n][1] = RD(rdB, 0, n, 1);
        }
        STAGE_A(1, 0, t1);
        PREDRAIN();
        BAR();
        MFMA_PHASE(0, 0, b01);
        BAR();

        // phase 2: read B[n2-3]; MFMA m0-3 x n2-3
#pragma unroll
        for (int n = 0; n < 2; ++n) {
            b23[n][0] = RD(rdB, 0, 2 + n, 0);
            b23[n][1] = RD(rdB, 0, 2 + n, 1);
        }
        STAGE_A(1, 1, t1);
        BAR();
        MFMA_PHASE(0, 2, b23);
        BAR();

        // phase 3: read A[m4-7]; MFMA m4-7 x n2-3
#pragma unroll
        for (int m = 0; m < 4; ++m) {
            aF[m][0] = RD(rdA, 0, 4 + m, 0);
            aF[m][1] = RD(rdA, 0, 4 + m, 1);
        }
        if (full) STAGE_B(0, 0, t2);
        BAR();
        MFMA_PHASE(4, 2, b23);
        BAR();

        // phase 4: no ds_read; MFMA m4-7 x n0-1 (b01 kept in regs)
        if (full) STAGE_B(0, 1, t2);
        BAR();
        MFMA_PHASE(4, 0, b01);
        if (full)
            asm volatile("s_waitcnt vmcnt(4)" ::: "memory");
        else
            asm volatile("s_waitcnt vmcnt(0)" ::: "memory");
        BAR();

        // phase 5: tile 2i+1 (buf1): read A[m0-3]+B[n0-1]
#pragma unroll
        for (int m = 0; m < 4; ++m) {
            aF[m][0] = RD(rdA, 1, m, 0);
            aF[m][1] = RD(rdA, 1, m, 1);
        }
#pragma unroll
        for (int n = 0; n < 2; ++n) {
            b01[n][0] = RD(rdB, 1, n, 0);
            b01[n][1] = RD(rdB, 1, n, 1);
        }
        if (full) STAGE_A(0, 0, t2);
        PREDRAIN();
        BAR();
        MFMA_PHASE(0, 0, b01);
        BAR();

        // phase 6: read B[n2-3]
#pragma unroll
        for (int n = 0; n < 2; ++n) {
            b23[n][0] = RD(rdB, 1, 2 + n, 0);
            b23[n][1] = RD(rdB, 1, 2 + n, 1);
        }
        if (full) STAGE_A(0, 1, t2);
        BAR();
        MFMA_PHASE(0, 2, b23);
        BAR();

        // phase 7: read A[m4-7]
#pragma unroll
        for (int m = 0; m < 4; ++m) {
            aF[m][0] = RD(rdA, 1, 4 + m, 0);
            aF[m][1] = RD(rdA, 1, 4 + m, 1);
        }
        if (full) STAGE_B(1, 0, t3);
        BAR();
        MFMA_PHASE(4, 2, b23);
        BAR();

        // phase 8: MFMA m4-7 x n0-1
        if (full) STAGE_B(1, 1, t3);
        BAR();
        MFMA_PHASE(4, 0, b01);
        if (full)
            asm volatile("s_waitcnt vmcnt(4)" ::: "memory");
        else
            asm volatile("s_waitcnt vmcnt(0)" ::: "memory");
        BAR();
    }

    // epilogue
    const int orow = brow + wr * 128 + ((lane >> 4) << 2);
    const int ocol = bcol + wc * 64 + (lane & 15);
#pragma unroll
    for (int m = 0; m < 8; ++m) {
#pragma unroll
        for (int j = 0; j < 4; ++j) {
            const int r = orow + m * 16 + j;
            const size_t ro = (size_t)r * Nout;
            if (EPI == 0) {
#pragma unroll
                for (int n = 0; n < 4; ++n) {
                    float v = acc[m][n][j];
                    float u = 1.5957691216057308f * (v + 0.044715f * v * v * v);
                    float g = v / (1.0f + __expf(-u));
                    hOut[ro + ocol + n * 16] = __float2bfloat16(g);
                }
            } else {
                const float sc = s[r];
#pragma unroll
                for (int n = 0; n < 4; ++n)
                    unsafeAtomicAdd(&fOut[ro + ocol + n * 16], sc * acc[m][n][j]);
            }
        }
    }
#undef STAGE_A
#undef STAGE_B
#undef BAR
#undef WAITLG
#undef PREDRAIN
#undef PIN
#undef RD
#undef MM_Q
#undef MFMA_PHASE
}

extern "C" void kernel_launch(void* const* d_in, const int* in_sizes, int n_in,
                              void* d_out, int out_size, void* d_ws, size_t ws_size,
                              hipStream_t stream) {
    const float* x = (const float*)d_in[0];
    // d_in[1] = scores (unused), d_in[3] = top_experts (unused)
    const float* ew = (const float*)d_in[2];
    const float* w1 = (const float*)d_in[4];
    const float* w2 = (const float*)d_in[5];
    float* out = (float*)d_out;

    char* ws = (char*)d_ws;
    float* s = (float*)ws;                                                    // 16 KB
    __hip_bfloat16* xb = (__hip_bfloat16*)(ws + 16384);                       // 8 MB
    __hip_bfloat16* w1t = (__hip_bfloat16*)(ws + 16384 + 8388608);            // 16 MB
    __hip_bfloat16* w2t = (__hip_bfloat16*)(ws + 16384 + 8388608 + 16777216); // 16 MB
    __hip_bfloat16* h = (__hip_bfloat16*)(ws + 16384 + 8388608 + 2 * 16777216); // 64 MB

    k_prep<<<1024, 256, 0, stream>>>(x, ew, xb, s, (TT * HID) / 4, TT);

    dim3 t1(INTER / 32, HID / 32);
    k_tcast<<<t1, 256, 0, stream>>>(w1, w1t, HID, INTER);
    dim3 t2(HID / 32, INTER / 32);
    k_tcast<<<t2, 256, 0, stream>>>(w2, w2t, INTER, HID);

    // GEMM1: [4096 x 1024] x [1024 x 8192] -> h (gelu, bf16)
    dim3 g1(INTER / 256, TT / 256, 1);  // 32 x 16
    k_gemm8<0><<<g1, 512, 0, stream>>>(xb, w1t, h, nullptr, nullptr, HID, HID / 64, INTER);

    // GEMM2: [4096 x 8192] x [8192 x 1024] -> out (f32, split-K=4 atomic combine)
    hipMemsetAsync(out, 0, (size_t)TT * HID * sizeof(float), stream);
    dim3 g2(HID / 256, TT / 256, 4);  // 4 x 16 x 4 = 256 blocks
    k_gemm8<1><<<g2, 512, 0, stream>>>(h, w2t, nullptr, out, s, INTER, 2048 / 64, HID);
}